// Round 8
// baseline (120.789 us; speedup 1.0000x reference)
//
#include <hip/hip_runtime.h>
#include <stdint.h>

// Problem constants (from reference setup_inputs)
#define NBOX 256
#define NC   32
#define ND   64
#define NH   64
#define NW   64
#define CD   16
#define CH   16
#define CW   16
#define NXCD 8
#define DHW  (ND * NH * NW)
// LDS: 3 buffers x 64 rows x 64 floats = 49152 B -> 3 blocks/CU

// ---- pre-kernel: stable counting-sort permutation of boxes by box_ind ----
__global__ __launch_bounds__(NBOX) void CropAndResize3D_perm_kernel(
    const int* __restrict__ box_ind, int* __restrict__ perm)
{
    __shared__ int nsh[NBOX];
    const int t = threadIdx.x;
    nsh[t] = box_ind[t];
    __syncthreads();
    const int n_t = nsh[t];
    int rank = 0;
    #pragma unroll 8
    for (int j = 0; j < NBOX; ++j) {
        const int n_j = nsh[j];
        rank += (n_j < n_t) || (n_j == n_t && j < t);
    }
    perm[rank] = t;
}

__global__ __launch_bounds__(256) void CropAndResize3D_89481348645400_kernel(
    const float* __restrict__ image,   // (N, C, D, H, W)
    const float* __restrict__ boxes,   // (NB, 6) = x1,y1,z1,x2,y2,z2
    const int*   __restrict__ box_ind, // (NB,)
    const int*   __restrict__ perm,    // (NB,) or null -> identity
    float*       __restrict__ out)     // (NB, C, CD, CH, CW)
{
    __shared__ float sh[3 * 64 * 64];  // 49152 B

    // XCD-aware swizzle (R1 win). With image-sorted perm, each XCD gets
    // ~32 boxes of ~one image (R7 win: FETCH at unique-bytes floor).
    const int nwg_per_xcd = (NBOX * CD) / NXCD;   // 512
    const int hw  = blockIdx.x;
    const int blk = (hw & (NXCD - 1)) * nwg_per_xcd + (hw >> 3);

    const int slot = blk >> 4;         // logical (sorted) box slot
    const int b = perm ? perm[slot] : slot;  // actual box id
    const int z = blk & 15;            // crop depth index
    const int t  = threadIdx.x;
    const int ty = t >> 4;             // out-y
    const int tx = t & 15;             // out-x / stage slot id

    const float bx1 = boxes[b*6+0], by1 = boxes[b*6+1], bz1 = boxes[b*6+2];
    const float bx2 = boxes[b*6+3], by2 = boxes[b*6+4], bz2 = boxes[b*6+5];
    const int   n   = box_ind[b];

    const float zstep = (bz2 - bz1) * 63.0f / 15.0f;
    const float ystep = (by2 - by1) * 63.0f / 15.0f;
    const float xstep = (bx2 - bx1) * 63.0f / 15.0f;  // >= 0 (boxes sorted)

    // z (block-uniform)
    const float zc = bz1 * 63.0f + (float)z * zstep;
    const bool  vz = (zc >= 0.0f) && (zc <= 63.0f);
    const float zq = fminf(fmaxf(zc, 0.0f), 63.0f);
    const int   z0 = (int)floorf(zq);
    const int   z1 = min(z0 + 1, ND - 1);
    const float fz = zq - (float)z0;

    // y (this thread)
    const float yc = by1 * 63.0f + (float)ty * ystep;
    const bool  vy = (yc >= 0.0f) && (yc <= 63.0f);
    const float yq = fminf(fmaxf(yc, 0.0f), 63.0f);
    const float fy = yq - floorf(yq);

    // x (this thread)
    const float xcf = bx1 * 63.0f + (float)tx * xstep;
    const bool  vx  = (xcf >= 0.0f) && (xcf <= 63.0f);
    const float xq  = fminf(fmaxf(xcf, 0.0f), 63.0f);
    const int   x0  = (int)floorf(xq);
    const int   x1  = min(x0 + 1, NW - 1);
    const float fx  = xq - (float)x0;

    const bool valid = vz && vy && vx;
    const float gz = 1.0f - fz, gy = 1.0f - fy, gx = 1.0f - fx;

    // x-window (block-uniform; xc monotone in tx since xstep >= 0)
    const float xcl = bx1 * 63.0f;
    const float xch = bx1 * 63.0f + 15.0f * xstep;
    const int x0min = (int)floorf(fminf(fmaxf(xcl, 0.0f), 63.0f));
    const int x1max = min((int)floorf(fminf(fmaxf(xch, 0.0f), 63.0f)) + 1, NW - 1);
    const int xlo4  = x0min & ~3;                  // 4-aligned window start
    const int G     = ((x1max - xlo4) >> 2) + 1;   // float4 groups, 1..16

    // staging (DMA): row r = zcorner*32 + yo*2 + ycorner; slot s holds global
    // group s ^ (r&7) [pre-swizzled SOURCE, linear LDS dest per rule #21].
    const int key = ty & 7;                        // == r&7 for r = k*16+ty
    const bool act = ((tx ^ key) < G);             // G active slots per row
    const int sx  = xlo4 + ((tx ^ key) << 2);      // swizzled global x start

    int soff0, soff1, soff2, soff3;
    {
        int tmp[4];
        #pragma unroll
        for (int k = 0; k < 4; ++k) {
            const int r   = k * 16 + ty;
            const int yo  = (r >> 1) & 15;
            const int yc_ = r & 1;
            const int zs  = (r >> 5) ? z1 : z0;
            const float yco = by1 * 63.0f + (float)yo * ystep;
            const float yqs = fminf(fmaxf(yco, 0.0f), 63.0f);
            const int   ys0 = (int)floorf(yqs);
            const int   ysel = yc_ ? min(ys0 + 1, NH - 1) : ys0;
            tmp[k] = (zs * NH + ysel) * NW + sx;
        }
        soff0 = tmp[0]; soff1 = tmp[1]; soff2 = tmp[2]; soff3 = tmp[3];
    }
    // wave-uniform LDS float offsets for the 4 DMA calls
    const int wb    = (ty & ~3) * 64;              // wave base row * 64
    const int ldsb0 = wb;
    const int ldsb1 = wb + 16 * 64;
    const int ldsb2 = wb + 32 * 64;
    const int ldsb3 = wb + 48 * 64;

    // compute-side swizzled LDS read addresses (channel-invariant)
    const int dx0 = x0 - xlo4;
    const int dx1 = x1 - xlo4;
    #define IDX(r, dx) ((r) * 64 + (((((dx) >> 2) ^ ((r) & 7))) << 2) + ((dx) & 3))
    const int a000 = IDX(2*ty    , dx0), a001 = IDX(2*ty    , dx1);
    const int a010 = IDX(2*ty + 1, dx0), a011 = IDX(2*ty + 1, dx1);
    const int a100 = IDX(32+2*ty , dx0), a101 = IDX(32+2*ty , dx1);
    const int a110 = IDX(33+2*ty , dx0), a111 = IDX(33+2*ty , dx1);
    #undef IDX

    const float* imgb = image + (size_t)n * (NC * DHW);
    float* op = out + (size_t)b * (NC * CD * CH * CW) + (z * CH + ty) * CW + tx;

    // c must be compile-time (full unroll) so (c%3) folds to an immediate.
    #define ISSUE(c)  do { if (act) {                                          \
        const float* p_ = imgb + (size_t)(c) * DHW;                            \
        float* l_ = sh + (((c) % 3) << 12);                                    \
        __builtin_amdgcn_global_load_lds(                                      \
            (const __attribute__((address_space(1))) uint32_t*)(p_ + soff0),   \
            (__attribute__((address_space(3))) uint32_t*)(l_ + ldsb0), 16, 0, 0); \
        __builtin_amdgcn_global_load_lds(                                      \
            (const __attribute__((address_space(1))) uint32_t*)(p_ + soff1),   \
            (__attribute__((address_space(3))) uint32_t*)(l_ + ldsb1), 16, 0, 0); \
        __builtin_amdgcn_global_load_lds(                                      \
            (const __attribute__((address_space(1))) uint32_t*)(p_ + soff2),   \
            (__attribute__((address_space(3))) uint32_t*)(l_ + ldsb2), 16, 0, 0); \
        __builtin_amdgcn_global_load_lds(                                      \
            (const __attribute__((address_space(1))) uint32_t*)(p_ + soff3),   \
            (__attribute__((address_space(3))) uint32_t*)(l_ + ldsb3), 16, 0, 0); \
    } } while (0)

    #define COMPUTE(c)  do {                                                   \
        const float* S_ = sh + (((c) % 3) << 12);                              \
        const float s000 = S_[a000], s001 = S_[a001];                          \
        const float s010 = S_[a010], s011 = S_[a011];                          \
        const float s100 = S_[a100], s101 = S_[a101];                          \
        const float s110 = S_[a110], s111 = S_[a111];                          \
        const float c00 = s000 * gx + s001 * fx;                               \
        const float c01 = s010 * gx + s011 * fx;                               \
        const float c10 = s100 * gx + s101 * fx;                               \
        const float c11 = s110 * gx + s111 * fx;                               \
        const float c0  = c00 * gy + c01 * fy;                                 \
        const float c1  = c10 * gy + c11 * fy;                                 \
        float v = c0 * gz + c1 * fz;                                           \
        v = valid ? v : 0.0f;                                                  \
        __builtin_nontemporal_store(v, op + (c) * (CD * CH * CW));             \
    } while (0)

    #define SBAR __builtin_amdgcn_sched_barrier(0)

    // prologue: fill all 3 buffers; wait for ch0 only (ch1,ch2 stay in flight)
    ISSUE(0);
    ISSUE(1);
    ISSUE(2);
    asm volatile("s_waitcnt vmcnt(8)" ::: "memory");
    __builtin_amdgcn_s_barrier();
    SBAR;

    // steady state: wait on a batch issued TWO iterations earlier (vmcnt(8)),
    // keeping 2 channel-batches in flight across the barriers.
    #pragma unroll
    for (int c = 0; c < NC; ++c) {
        COMPUTE(c);
        if (c + 1 < NC) {
            SBAR;
            __builtin_amdgcn_s_barrier();          // buf c%3 free for overwrite
            SBAR;
            if (c + 3 < NC) {
                ISSUE(c + 3);                      // -> buf c%3
                asm volatile("s_waitcnt vmcnt(8)" ::: "memory");  // c+1 done
            } else if (c + 2 < NC) {
                asm volatile("s_waitcnt vmcnt(4)" ::: "memory");  // c+1 done
            } else {
                asm volatile("s_waitcnt vmcnt(0)" ::: "memory");  // tail drain
            }
            SBAR;
            __builtin_amdgcn_s_barrier();          // c+1 rows visible to all
            SBAR;
        }
    }

    #undef ISSUE
    #undef COMPUTE
    #undef SBAR
}

extern "C" void kernel_launch(void* const* d_in, const int* in_sizes, int n_in,
                              void* d_out, int out_size, void* d_ws, size_t ws_size,
                              hipStream_t stream) {
    const float* image   = (const float*)d_in[0];
    const float* boxes   = (const float*)d_in[1];
    const int*   box_ind = (const int*)d_in[2];
    float*       out     = (float*)d_out;

    int* perm = nullptr;
    if (ws_size >= NBOX * sizeof(int)) {
        perm = (int*)d_ws;
        CropAndResize3D_perm_kernel<<<1, NBOX, 0, stream>>>(box_ind, perm);
    }

    const int blocks = NBOX * CD;  // 4096
    CropAndResize3D_89481348645400_kernel<<<blocks, 256, 0, stream>>>(
        image, boxes, box_ind, perm, out);
}

// Round 9
// 120.219 us; speedup vs baseline: 1.0047x; 1.0047x over previous
//
#include <hip/hip_runtime.h>
#include <stdint.h>

// Problem constants (from reference setup_inputs)
#define NBOX 256
#define NC   32
#define ND   64
#define NH   64
#define NW   64
#define CD   16
#define CH   16
#define CW   16
#define NXCD 8
#define DHW  (ND * NH * NW)
// LDS: 2 buffers x 64 rows x 64 floats = 32768 B; rows 16w..16w+15 are
// PRIVATE to wave w (stager == consumer) -> no s_barrier anywhere.

// ---- pre-kernel: stable counting-sort permutation of boxes by box_ind ----
__global__ __launch_bounds__(NBOX) void CropAndResize3D_perm_kernel(
    const int* __restrict__ box_ind, int* __restrict__ perm)
{
    __shared__ int nsh[NBOX];
    const int t = threadIdx.x;
    nsh[t] = box_ind[t];
    __syncthreads();
    const int n_t = nsh[t];
    int rank = 0;
    #pragma unroll 8
    for (int j = 0; j < NBOX; ++j) {
        const int n_j = nsh[j];
        rank += (n_j < n_t) || (n_j == n_t && j < t);
    }
    perm[rank] = t;
}

__global__ __launch_bounds__(256) void CropAndResize3D_89481348645400_kernel(
    const float* __restrict__ image,   // (N, C, D, H, W)
    const float* __restrict__ boxes,   // (NB, 6) = x1,y1,z1,x2,y2,z2
    const int*   __restrict__ box_ind, // (NB,)
    const int*   __restrict__ perm,    // (NB,) or null -> identity
    float*       __restrict__ out)     // (NB, C, CD, CH, CW)
{
    __shared__ float sh[2 * 64 * 64];  // 32 KB

    // XCD-aware swizzle (R1) + image-sorted perm (R7): FETCH at unique-bytes floor.
    const int nwg_per_xcd = (NBOX * CD) / NXCD;   // 512
    const int hwid = blockIdx.x;
    const int blk = (hwid & (NXCD - 1)) * nwg_per_xcd + (hwid >> 3);

    const int slot = blk >> 4;
    const int b = perm ? perm[slot] : slot;
    const int z = blk & 15;
    const int t  = threadIdx.x;
    const int w  = t >> 6;             // wave id 0..3
    const int l  = t & 63;             // lane
    const int q  = l >> 4;             // y-sub within wave (0..3)
    const int tx = l & 15;             // out-x / stage slot
    const int ty = (w << 2) | q;       // out-y  (== t>>4)

    const float bx1 = boxes[b*6+0], by1 = boxes[b*6+1], bz1 = boxes[b*6+2];
    const float bx2 = boxes[b*6+3], by2 = boxes[b*6+4], bz2 = boxes[b*6+5];
    const int   n   = box_ind[b];

    const float zstep = (bz2 - bz1) * 63.0f / 15.0f;
    const float ystep = (by2 - by1) * 63.0f / 15.0f;
    const float xstep = (bx2 - bx1) * 63.0f / 15.0f;  // >= 0 (boxes sorted)

    // z (block-uniform)
    const float zc = bz1 * 63.0f + (float)z * zstep;
    const bool  vz = (zc >= 0.0f) && (zc <= 63.0f);
    const float zq = fminf(fmaxf(zc, 0.0f), 63.0f);
    const int   z0 = (int)floorf(zq);
    const int   z1 = min(z0 + 1, ND - 1);
    const float fz = zq - (float)z0;

    // y (this thread)
    const float yc = by1 * 63.0f + (float)ty * ystep;
    const bool  vy = (yc >= 0.0f) && (yc <= 63.0f);
    const float yq = fminf(fmaxf(yc, 0.0f), 63.0f);
    const float fy = yq - floorf(yq);

    // x (this thread)
    const float xcf = bx1 * 63.0f + (float)tx * xstep;
    const bool  vx  = (xcf >= 0.0f) && (xcf <= 63.0f);
    const float xq  = fminf(fmaxf(xcf, 0.0f), 63.0f);
    const int   x0  = (int)floorf(xq);
    const int   x1  = min(x0 + 1, NW - 1);
    const float fx  = xq - (float)x0;

    const bool valid = vz && vy && vx;
    const float gz = 1.0f - fz, gy = 1.0f - fy, gx = 1.0f - fx;

    // x-window (block-uniform)
    const float xcl = bx1 * 63.0f;
    const float xch = bx1 * 63.0f + 15.0f * xstep;
    const int x0min = (int)floorf(fminf(fmaxf(xcl, 0.0f), 63.0f));
    const int x1max = min((int)floorf(fminf(fmaxf(xch, 0.0f), 63.0f)) + 1, NW - 1);
    const int xlo4  = x0min & ~3;
    const int G     = ((x1max - xlo4) >> 2) + 1;   // 1..16

    // ---- wave-private staging: local row rho = k*4 + q (k = DMA call id) ----
    // rho decodes as: zcorner = rho>>3, ypair = (rho>>1)&3, ycorner = rho&1.
    // Slot s holds global group s ^ (rho&7); inactive lanes re-read window
    // start (same cache line -> no extra FETCH, keeps vmcnt exact).
    int soff0, soff1, soff2, soff3;
    {
        int tmp[4];
        #pragma unroll
        for (int k = 0; k < 4; ++k) {
            const int rho = k * 4 + q;
            const int zc_ = rho >> 3;
            const int qq  = (rho >> 1) & 3;
            const int yc_ = rho & 1;
            const int zs  = zc_ ? z1 : z0;
            const int yo  = (w << 2) | qq;
            const float yco = by1 * 63.0f + (float)yo * ystep;
            const float yqs = fminf(fmaxf(yco, 0.0f), 63.0f);
            const int   ys0 = (int)floorf(yqs);
            const int   ysel = yc_ ? min(ys0 + 1, NH - 1) : ys0;
            const int   key = rho & 7;
            const int   g   = tx ^ key;
            const int   sx  = (g < G) ? (xlo4 + (g << 2)) : xlo4;
            tmp[k] = (zs * NH + ysel) * NW + sx;
        }
        soff0 = tmp[0]; soff1 = tmp[1]; soff2 = tmp[2]; soff3 = tmp[3];
    }
    const int wbF = w << 10;           // wave LDS base (floats): w*16 rows*64

    // compute-side swizzled addresses; z1 rows are exactly +512 floats
    // (same swizzle key since (rho+8)&7 == rho&7) -> ds_read2st64 mergeable.
    const int dx0 = x0 - xlo4;
    const int dx1 = x1 - xlo4;
    #define SWZ(rho, dx) ((((((dx) >> 2) ^ ((rho) & 7))) << 2) | ((dx) & 3))
    const int a000 = wbF + (2*q    ) * 64 + SWZ(2*q    , dx0);
    const int a001 = wbF + (2*q    ) * 64 + SWZ(2*q    , dx1);
    const int a010 = wbF + (2*q + 1) * 64 + SWZ(2*q + 1, dx0);
    const int a011 = wbF + (2*q + 1) * 64 + SWZ(2*q + 1, dx1);
    #undef SWZ

    const float* imgb = image + (size_t)n * (NC * DHW);
    float* op = out + (size_t)b * (NC * CD * CH * CW) + (z * CH + ty) * CW + tx;

    #define ISSUE(c)  do {                                                     \
        const float* p_ = imgb + (size_t)(c) * DHW;                            \
        float* l_ = sh + (((c) & 1) << 12) + wbF;                              \
        __builtin_amdgcn_global_load_lds(                                      \
            (const __attribute__((address_space(1))) uint32_t*)(p_ + soff0),   \
            (__attribute__((address_space(3))) uint32_t*)(l_      ), 16, 0, 0);\
        __builtin_amdgcn_global_load_lds(                                      \
            (const __attribute__((address_space(1))) uint32_t*)(p_ + soff1),   \
            (__attribute__((address_space(3))) uint32_t*)(l_ + 256), 16, 0, 0);\
        __builtin_amdgcn_global_load_lds(                                      \
            (const __attribute__((address_space(1))) uint32_t*)(p_ + soff2),   \
            (__attribute__((address_space(3))) uint32_t*)(l_ + 512), 16, 0, 0);\
        __builtin_amdgcn_global_load_lds(                                      \
            (const __attribute__((address_space(1))) uint32_t*)(p_ + soff3),   \
            (__attribute__((address_space(3))) uint32_t*)(l_ + 768), 16, 0, 0);\
    } while (0)

    #define COMPUTE(c)  do {                                                   \
        const float* S_ = sh + (((c) & 1) << 12);                              \
        const float s000 = S_[a000], s100 = S_[a000 + 512];                    \
        const float s001 = S_[a001], s101 = S_[a001 + 512];                    \
        const float s010 = S_[a010], s110 = S_[a010 + 512];                    \
        const float s011 = S_[a011], s111 = S_[a011 + 512];                    \
        const float c00 = s000 * gx + s001 * fx;                               \
        const float c01 = s010 * gx + s011 * fx;                               \
        const float c10 = s100 * gx + s101 * fx;                               \
        const float c11 = s110 * gx + s111 * fx;                               \
        const float c0  = c00 * gy + c01 * fy;                                 \
        const float c1  = c10 * gy + c11 * fy;                                 \
        float v = c0 * gz + c1 * fz;                                           \
        v = valid ? v : 0.0f;                                                  \
        __builtin_nontemporal_store(v, op + (c) * (CD * CH * CW));             \
    } while (0)

    // prologue: fill both buffers for this wave; NO barriers anywhere.
    ISSUE(0);
    ISSUE(1);

    // Per-wave pipeline. vmcnt bookkeeping (loads+stores share the counter):
    //   iter 0 : outstanding {DMA0 x4, DMA1 x4}            -> wait vmcnt(4)
    //   iter c : {st(c-2)?, DMAc x4, st(c-1), DMA(c+1) x4} -> wait vmcnt(5)
    //   iter 31: {DMA31 x4, st30}                          -> wait vmcnt(1)
    #pragma unroll
    for (int c = 0; c < NC; ++c) {
        if (c == 0)      asm volatile("s_waitcnt vmcnt(4)" ::: "memory");
        else if (c < 31) asm volatile("s_waitcnt vmcnt(5)" ::: "memory");
        else             asm volatile("s_waitcnt vmcnt(1)" ::: "memory");
        __builtin_amdgcn_sched_barrier(0);
        COMPUTE(c);
        // ds_read results are consumed by the FMAs above (compiler-inserted
        // lgkmcnt waits) before the DMA below can overwrite buf[c&1].
        asm volatile("s_waitcnt lgkmcnt(0)" ::: "memory");
        __builtin_amdgcn_sched_barrier(0);
        if (c + 2 < NC) ISSUE(c + 2);
    }

    #undef ISSUE
    #undef COMPUTE
}

extern "C" void kernel_launch(void* const* d_in, const int* in_sizes, int n_in,
                              void* d_out, int out_size, void* d_ws, size_t ws_size,
                              hipStream_t stream) {
    const float* image   = (const float*)d_in[0];
    const float* boxes   = (const float*)d_in[1];
    const int*   box_ind = (const int*)d_in[2];
    float*       out     = (float*)d_out;

    int* perm = nullptr;
    if (ws_size >= NBOX * sizeof(int)) {
        perm = (int*)d_ws;
        CropAndResize3D_perm_kernel<<<1, NBOX, 0, stream>>>(box_ind, perm);
    }

    const int blocks = NBOX * CD;  // 4096
    CropAndResize3D_89481348645400_kernel<<<blocks, 256, 0, stream>>>(
        image, boxes, box_ind, perm, out);
}